// Round 5
// baseline (66.444 us; speedup 1.0000x reference)
//
#include <hip/hip_runtime.h>

#define BB 4096
#define TT 80
#define VV 10000
#define EE 100
#define HH 64
#define STR 72   // _Float16 row stride: 144 B/row -> reads 2-way max, writes 2-way

typedef _Float16 f16x8 __attribute__((ext_vector_type(8)));
typedef __attribute__((ext_vector_type(4))) float f4v;   // 4 fp32
typedef __attribute__((ext_vector_type(4))) int i4v;     // 4 i32

#define MFMA(a, b, c) __builtin_amdgcn_mfma_f32_16x16x32_f16((a), (b), (c), 0, 0, 0)

// Raw barrier: drains LDS ops (lgkm) but lets global gather loads stay in
// flight across the barrier (no vmcnt(0) drain like __syncthreads emits).
#define BAR() do { asm volatile("s_waitcnt lgkmcnt(0)" ::: "memory"); \
                   __builtin_amdgcn_s_barrier();                      \
                   asm volatile("" ::: "memory"); } while (0)

__device__ __forceinline__ unsigned f2u(float f) { return __float_as_uint(f); }
__device__ __forceinline__ float u2f(unsigned u) { return __uint_as_float(u); }

// tanh(x) = 1 - 2/(exp(2x)+1). No clamp: +big -> e=inf -> 1; -big -> e=0 -> -1.
__device__ __forceinline__ float fast_tanh(float x) {
    float e = __builtin_amdgcn_exp2f(x * 2.8853900817779268f); // exp(2x)
    return 1.0f - 2.0f * __builtin_amdgcn_rcpf(e + 1.0f);
}

// B-fragment (hi/lo fp16) for W[k][c]: frag elem i <- W[32*kf + 8*g + i][c]
__device__ __forceinline__ void load_wfrag(const float* __restrict__ W, int kf, int g,
                                           int c, f16x8& hi, f16x8& lo) {
    union { _Float16 h[8]; f16x8 v; } th, tl;
#pragma unroll
    for (int i = 0; i < 8; ++i) {
        float wv = W[(32 * kf + 8 * g + i) * HH + c];
        _Float16 hf = (_Float16)wv;          // RNE
        th.h[i] = hf;
        tl.h[i] = (_Float16)(wv - (float)hf);
    }
    hi = th.v;
    lo = tl.v;
}

// emb2[v][j] = sum_e emb[v][e] * Wx0[e][j] + b0[j]
__global__ __launch_bounds__(256) void emb2_kernel(const float* __restrict__ emb,
                                                   const float* __restrict__ Wx0,
                                                   const float* __restrict__ b0,
                                                   float* __restrict__ emb2) {
    __shared__ float embL[16 * EE];
    const int v0 = blockIdx.x * 16;
    for (int i = threadIdx.x; i < 16 * EE; i += 256)
        embL[i] = emb[(size_t)v0 * EE + i];
    __syncthreads();
    const int wid = threadIdx.x >> 6;
    const int lane = threadIdx.x & 63;
    const float bb = b0[lane];
    float a0 = bb, a1 = bb, a2 = bb, a3 = bb;
    const float* e0 = &embL[(4 * wid) * EE];
#pragma unroll 4
    for (int e = 0; e < EE; ++e) {
        float w = Wx0[e * HH + lane];
        a0 = fmaf(e0[e], w, a0);
        a1 = fmaf(e0[e + EE], w, a1);
        a2 = fmaf(e0[e + 2 * EE], w, a2);
        a3 = fmaf(e0[e + 3 * EE], w, a3);
    }
    const int r = v0 + 4 * wid;
    emb2[(size_t)(r + 0) * HH + lane] = a0;
    emb2[(size_t)(r + 1) * HH + lane] = a1;
    emb2[(size_t)(r + 2) * HH + lane] = a2;
    emb2[(size_t)(r + 3) * HH + lane] = a3;
}

// 32-row / 8-wave blocks (2 waves per SIMD -> latency overlap), fp16 state.
// Wave w8: row-half rh = w8>>2 (rows 16rh..16rh+15), column tile = w8&3.
//   h0(p)   = tanh(x(p) + h0(p-1)@Wh0)
//   h1(p-1) = tanh(b1 + h0(p-1)@Wx1 + h1(p-2)@Wh1)
// State: single fp16 (RNE) in double-buffered LDS; weights hi/lo fp16 in
// registers (12 MFMA/phase). One raw barrier per phase (lgkm drain only).
__global__ __launch_bounds__(512, 2) void rnn_pipe(
    const int* __restrict__ tokens, const float* __restrict__ emb2,
    const float* __restrict__ Wh0, const float* __restrict__ Wx1,
    const float* __restrict__ Wh1, const float* __restrict__ b1,
    const float* __restrict__ Wout, const float* __restrict__ bout,
    float* __restrict__ out) {
    __shared__ __align__(16) _Float16 H0[2][32][STR];
    __shared__ __align__(16) _Float16 H1[2][32][STR];
    __shared__ __align__(16) int tokT[TT][32];   // [t][row], byte-scaled (<<8)

    const int tid = threadIdx.x;
    const int w8 = tid >> 6;         // 0..7
    const int l = tid & 63;
    const int g = l >> 4;
    const int r16 = l & 15;
    const int tile = w8 & 3;
    const int rh = w8 >> 2;          // row half: 0 or 1
    const int c = 16 * tile + r16;   // my output column
    const int rbase = 16 * rh;       // my row-half base
    const int R = blockIdx.x * 32;   // base batch row

    for (int i = tid; i < 32 * TT; i += 512) {
        int r = i / TT, t = i - r * TT;
        tokT[t][r] = tokens[R * TT + i] << 8;
    }

    f16x8 wh0h[2], wh0l[2], wx1h[2], wx1l[2], wh1h[2], wh1l[2];
    load_wfrag(Wh0, 0, g, c, wh0h[0], wh0l[0]);
    load_wfrag(Wh0, 1, g, c, wh0h[1], wh0l[1]);
    load_wfrag(Wx1, 0, g, c, wx1h[0], wx1l[0]);
    load_wfrag(Wx1, 1, g, c, wx1h[1], wx1l[1]);
    load_wfrag(Wh1, 0, g, c, wh1h[0], wh1l[0]);
    load_wfrag(Wh1, 1, g, c, wh1h[1], wh1l[1]);
    const float b1j = b1[c];
    const float woj = Wout[l];
    const f4v z4 = {0.f, 0.f, 0.f, 0.f};
    const char* ebase = (const char*)emb2 + 4 * c;

    BAR();   // tokens staged

    f16x8 a0[2] = {(f16x8)0, (f16x8)0};   // h0(p-1) fragments (kf=0,1)
    f16x8 a1[2] = {(f16x8)0, (f16x8)0};   // h1(p-2) fragments

    f4v xc, xn;
    {
        i4v tk0 = *(const i4v*)&tokT[0][rbase + 4 * g];
        i4v tk1 = *(const i4v*)&tokT[1][rbase + 4 * g];
#pragma unroll
        for (int q = 0; q < 4; ++q)
            xc[q] = *(const float*)(ebase + tk0[q]);
#pragma unroll
        for (int q = 0; q < 4; ++q)
            xn[q] = *(const float*)(ebase + tk1[q]);
    }

    // ---- phase 0: h0(0) = tanh(x0) ----
#pragma unroll
    for (int q = 0; q < 4; ++q)
        H0[0][rbase + 4 * g + q][c] = (_Float16)fast_tanh(xc[q]);
    xc = xn;
    BAR();
    a0[0] = *(const f16x8*)&H0[0][rbase + r16][8 * g];
    a0[1] = *(const f16x8*)&H0[0][rbase + r16][32 + 8 * g];
    // a1 stays zero (h1(-1) = 0)

    // ---- main loop p = 1..TT-2 ----
#pragma unroll 2
    for (int p = 1; p <= TT - 2; ++p) {
        const int par = p & 1;
        // prefetch x(p+1): gathers float across BAR, waited at next use
        i4v tk = *(const i4v*)&tokT[p + 1][rbase + 4 * g];
#pragma unroll
        for (int q = 0; q < 4; ++q)
            xn[q] = *(const float*)(ebase + tk[q]);
        // L0: h0(p) — 2 chains of 2
        f4v A1 = {xc[0], xc[1], xc[2], xc[3]};
        A1 = MFMA(a0[0], wh0h[0], A1);
        A1 = MFMA(a0[1], wh0h[1], A1);
        f4v A2 = MFMA(a0[0], wh0l[0], z4);
        A2 = MFMA(a0[1], wh0l[1], A2);
        // L1: h1(p-1) — 4 chains of 2 (reuses a0 fragments)
        f4v C1 = {b1j, b1j, b1j, b1j};
        C1 = MFMA(a0[0], wx1h[0], C1);
        C1 = MFMA(a0[1], wx1h[1], C1);
        f4v C2 = MFMA(a0[0], wx1l[0], z4);
        C2 = MFMA(a0[1], wx1l[1], C2);
        f4v C3 = MFMA(a1[0], wh1h[0], z4);
        C3 = MFMA(a1[1], wh1h[1], C3);
        f4v C4 = MFMA(a1[0], wh1l[0], z4);
        C4 = MFMA(a1[1], wh1l[1], C4);
        f4v acc0 = A1 + A2;
        f4v acc1 = (C1 + C2) + (C3 + C4);
#pragma unroll
        for (int q = 0; q < 4; ++q) {
            H0[par][rbase + 4 * g + q][c] = (_Float16)fast_tanh(acc0[q]);
            H1[par][rbase + 4 * g + q][c] = (_Float16)fast_tanh(acc1[q]);
        }
        xc = xn;
        BAR();
        a0[0] = *(const f16x8*)&H0[par][rbase + r16][8 * g];
        a0[1] = *(const f16x8*)&H0[par][rbase + r16][32 + 8 * g];
        a1[0] = *(const f16x8*)&H1[par][rbase + r16][8 * g];
        a1[1] = *(const f16x8*)&H1[par][rbase + r16][32 + 8 * g];
    }

    // ---- p = TT-1 = 79 (par 1): both layers, no prefetch ----
    {
        f4v A1 = {xc[0], xc[1], xc[2], xc[3]};
        A1 = MFMA(a0[0], wh0h[0], A1);
        A1 = MFMA(a0[1], wh0h[1], A1);
        f4v A2 = MFMA(a0[0], wh0l[0], z4);
        A2 = MFMA(a0[1], wh0l[1], A2);
        f4v C1 = {b1j, b1j, b1j, b1j};
        C1 = MFMA(a0[0], wx1h[0], C1);
        C1 = MFMA(a0[1], wx1h[1], C1);
        f4v C2 = MFMA(a0[0], wx1l[0], z4);
        C2 = MFMA(a0[1], wx1l[1], C2);
        f4v C3 = MFMA(a1[0], wh1h[0], z4);
        C3 = MFMA(a1[1], wh1h[1], C3);
        f4v C4 = MFMA(a1[0], wh1l[0], z4);
        C4 = MFMA(a1[1], wh1l[1], C4);
        f4v acc0 = A1 + A2;
        f4v acc1 = (C1 + C2) + (C3 + C4);
#pragma unroll
        for (int q = 0; q < 4; ++q) {
            H0[1][rbase + 4 * g + q][c] = (_Float16)fast_tanh(acc0[q]);
            H1[1][rbase + 4 * g + q][c] = (_Float16)fast_tanh(acc1[q]);
        }
        BAR();
        a0[0] = *(const f16x8*)&H0[1][rbase + r16][8 * g];
        a0[1] = *(const f16x8*)&H0[1][rbase + r16][32 + 8 * g];
        a1[0] = *(const f16x8*)&H1[1][rbase + r16][8 * g];
        a1[1] = *(const f16x8*)&H1[1][rbase + r16][32 + 8 * g];
    }

    // ---- p = TT = 80: L1 only -> h1(79) into buffer 0 ----
    {
        f4v C1 = {b1j, b1j, b1j, b1j};
        C1 = MFMA(a0[0], wx1h[0], C1);
        C1 = MFMA(a0[1], wx1h[1], C1);
        f4v C2 = MFMA(a0[0], wx1l[0], z4);
        C2 = MFMA(a0[1], wx1l[1], C2);
        f4v C3 = MFMA(a1[0], wh1h[0], z4);
        C3 = MFMA(a1[1], wh1h[1], C3);
        f4v C4 = MFMA(a1[0], wh1l[0], z4);
        C4 = MFMA(a1[1], wh1l[1], C4);
        f4v acc1 = (C1 + C2) + (C3 + C4);
#pragma unroll
        for (int q = 0; q < 4; ++q)
            H1[0][rbase + 4 * g + q][c] = (_Float16)fast_tanh(acc1[q]);
        BAR();
    }

    // Epilogue: out = sigmoid(h1(79) @ Wout + bout). Wave w8 -> rows 4w8..4w8+3.
#pragma unroll
    for (int q = 0; q < 4; ++q) {
        int row = 4 * w8 + q;
        float v = (float)H1[0][row][l];
        float pp = v * woj;
#pragma unroll
        for (int off = 32; off > 0; off >>= 1) pp += __shfl_xor(pp, off, 64);
        if (l == 0) {
            float logit = pp + bout[0];
            out[R + row] = __builtin_amdgcn_rcpf(
                1.0f + __builtin_amdgcn_exp2f(-1.4426950408889634f * logit));
        }
    }
}

extern "C" void kernel_launch(void* const* d_in, const int* in_sizes, int n_in,
                              void* d_out, int out_size, void* d_ws, size_t ws_size,
                              hipStream_t stream) {
    const int*   tokens = (const int*)  d_in[0];
    const float* emb    = (const float*)d_in[1];
    const float* Wx0    = (const float*)d_in[2];
    const float* Wh0    = (const float*)d_in[3];
    const float* b0     = (const float*)d_in[4];
    const float* Wx1    = (const float*)d_in[5];
    const float* Wh1    = (const float*)d_in[6];
    const float* b1     = (const float*)d_in[7];
    const float* Wout   = (const float*)d_in[8];
    const float* bout   = (const float*)d_in[9];
    float* out  = (float*)d_out;
    float* emb2 = (float*)d_ws;   // VV*HH floats = 2.56 MB

    emb2_kernel<<<VV / 16, 256, 0, stream>>>(emb, Wx0, b0, emb2);
    rnn_pipe<<<BB / 32, 512, 0, stream>>>(tokens, emb2, Wh0, Wx1, Wh1, b1,
                                          Wout, bout, out);
}

// Round 6
// 48.842 us; speedup vs baseline: 1.3604x; 1.3604x over previous
//
#include <hip/hip_runtime.h>

#define BB 4096
#define TT 80
#define VV 10000
#define EE 100
#define HH 64
#define STR 68   // fp16 row stride: 136 B/row -> 2 (mod 32) dword skew; read and
                 // write bursts both land at the 32-bank minimum (verified R4 pattern)

typedef _Float16 f16x8 __attribute__((ext_vector_type(8)));
typedef _Float16 f16x4 __attribute__((ext_vector_type(4)));
typedef __attribute__((ext_vector_type(4))) float f4v;   // 4 fp32

// Transposed compute: D = A(W^T frag) * B(state frag) + C, so D's lane layout is
// (batch row = l&15, 4 adjacent hidden cols = 4*(l>>4)+q)
#define MFMA(w, s, c) __builtin_amdgcn_mfma_f32_16x16x32_f16((w), (s), (c), 0, 0, 0)

// Raw barrier: drains LDS ops (lgkm) but lets global gather loads stay in
// flight across the barrier (no vmcnt(0) drain like __syncthreads emits).
#define BAR() do { asm volatile("s_waitcnt lgkmcnt(0)" ::: "memory"); \
                   __builtin_amdgcn_s_barrier();                      \
                   asm volatile("" ::: "memory"); } while (0)

// tanh(x) = 1 - 2/(exp(2x)+1). No clamp: +big -> e=inf -> 1; -big -> e=0 -> -1.
__device__ __forceinline__ float fast_tanh(float x) {
    float e = __builtin_amdgcn_exp2f(x * 2.8853900817779268f); // exp(2x)
    return 1.0f - 2.0f * __builtin_amdgcn_rcpf(e + 1.0f);
}

// Weight fragment (hi/lo fp16) for W[k][c]: frag elem i <- W[32*kf + 8*g + i][c].
// Passed as the A operand (it is W^T[m=c][k] in the transposed compute);
// bit-identical to the B-fragment proven in rounds 0-5.
__device__ __forceinline__ void load_wfrag(const float* __restrict__ W, int kf, int g,
                                           int c, f16x8& hi, f16x8& lo) {
    union { _Float16 h[8]; f16x8 v; } th, tl;
#pragma unroll
    for (int i = 0; i < 8; ++i) {
        float wv = W[(32 * kf + 8 * g + i) * HH + c];
        _Float16 hf = (_Float16)wv;          // RNE
        th.h[i] = hf;
        tl.h[i] = (_Float16)(wv - (float)hf);
    }
    hi = th.v;
    lo = tl.v;
}

// emb2[v][j] = sum_e emb[v][e] * Wx0[e][j] + b0[j]
__global__ __launch_bounds__(256) void emb2_kernel(const float* __restrict__ emb,
                                                   const float* __restrict__ Wx0,
                                                   const float* __restrict__ b0,
                                                   float* __restrict__ emb2) {
    __shared__ float embL[16 * EE];
    const int v0 = blockIdx.x * 16;
    for (int i = threadIdx.x; i < 16 * EE; i += 256)
        embL[i] = emb[(size_t)v0 * EE + i];
    __syncthreads();
    const int wid = threadIdx.x >> 6;
    const int lane = threadIdx.x & 63;
    const float bb = b0[lane];
    float a0 = bb, a1 = bb, a2 = bb, a3 = bb;
    const float* e0 = &embL[(4 * wid) * EE];
#pragma unroll 4
    for (int e = 0; e < EE; ++e) {
        float w = Wx0[e * HH + lane];
        a0 = fmaf(e0[e], w, a0);
        a1 = fmaf(e0[e + EE], w, a1);
        a2 = fmaf(e0[e + 2 * EE], w, a2);
        a3 = fmaf(e0[e + 3 * EE], w, a3);
    }
    const int r = v0 + 4 * wid;
    emb2[(size_t)(r + 0) * HH + lane] = a0;
    emb2[(size_t)(r + 1) * HH + lane] = a1;
    emb2[(size_t)(r + 2) * HH + lane] = a2;
    emb2[(size_t)(r + 3) * HH + lane] = a3;
}

// Transposed-MFMA pipeline: 256 blocks, 4 waves, 16 rows/block. Wave owns one
// 16-hidden-col tile of BOTH layers, computing h^T = W^T @ h^T:
//   h0(p)^T   = tanh(x(p)^T + Wh0^T @ h0(p-1)^T)
//   h1(p-1)^T = tanh(b1 + Wx1^T @ h0(p-1)^T + Wh1^T @ h1(p-2)^T)
// D-layout gives each lane 4 CONTIGUOUS hidden cols of one batch row ->
// state write = 1 packed b64 per state, x-gather = 1 dwordx4 per lane.
// One raw barrier per phase; fp16 state, hi/lo fp16 weights (12 MFMA/phase).
__global__ __launch_bounds__(256, 1) void rnn_pipe(
    const int* __restrict__ tokens, const float* __restrict__ emb2,
    const float* __restrict__ Wh0, const float* __restrict__ Wx1,
    const float* __restrict__ Wh1, const float* __restrict__ b1,
    const float* __restrict__ Wout, const float* __restrict__ bout,
    float* __restrict__ out) {
    __shared__ __align__(16) _Float16 H0[2][16][STR];
    __shared__ __align__(16) _Float16 H1[2][16][STR];
    __shared__ __align__(16) int tokT[TT][16];   // [t][row], byte-scaled (<<8)
    __shared__ float Pred[4][16];

    const int tid = threadIdx.x;
    const int wid = tid >> 6;        // 0..3 : hidden-column tile
    const int l = tid & 63;
    const int g = l >> 4;
    const int r16 = l & 15;          // my batch row (D/B col index)
    const int c = 16 * wid + r16;    // weight column for fragment loads
    const int R = blockIdx.x * 16;   // base batch row

    for (int i = tid; i < 16 * TT; i += 256) {
        int r = i / TT, t = i - r * TT;              // coalesced global read
        tokT[t][r] = tokens[R * TT + i] << 8;
    }

    f16x8 wh0h[2], wh0l[2], wx1h[2], wx1l[2], wh1h[2], wh1l[2];
    load_wfrag(Wh0, 0, g, c, wh0h[0], wh0l[0]);
    load_wfrag(Wh0, 1, g, c, wh0h[1], wh0l[1]);
    load_wfrag(Wx1, 0, g, c, wx1h[0], wx1l[0]);
    load_wfrag(Wx1, 1, g, c, wx1h[1], wx1l[1]);
    load_wfrag(Wh1, 0, g, c, wh1h[0], wh1l[0]);
    load_wfrag(Wh1, 1, g, c, wh1h[1], wh1l[1]);
    const int jcol = 16 * wid + 4 * g;           // my 4 hidden cols
    const f4v b1v = *(const f4v*)&b1[jcol];
    const f4v wov = *(const f4v*)&Wout[jcol];
    const f4v z4 = {0.f, 0.f, 0.f, 0.f};
    const char* ebase = (const char*)emb2 + (size_t)jcol * 4;

    BAR();   // tokens staged

    f16x8 a0[2] = {(f16x8)0, (f16x8)0};   // h0(p-1)^T fragments (kf=0,1)
    f16x8 a1[2] = {(f16x8)0, (f16x8)0};   // h1(p-2)^T fragments

    f4v xc, xn;
    {
        int tb0 = tokT[0][r16];
        int tb1 = tokT[1][r16];
        xc = *(const f4v*)(ebase + tb0);   // x(0)[r16][jcol..jcol+3]
        xn = *(const f4v*)(ebase + tb1);
    }

    // ---- phase 0: h0(0) = tanh(x0) ----
    {
        f16x4 ph;
#pragma unroll
        for (int q = 0; q < 4; ++q) ph[q] = (_Float16)fast_tanh(xc[q]);
        *(f16x4*)&H0[0][r16][jcol] = ph;           // one b64 write
    }
    xc = xn;
    BAR();
    a0[0] = *(const f16x8*)&H0[0][r16][8 * g];
    a0[1] = *(const f16x8*)&H0[0][r16][32 + 8 * g];
    // a1 stays zero (h1(-1) = 0)

    // ---- main loop p = 1..TT-2 ----
#pragma unroll 2
    for (int p = 1; p <= TT - 2; ++p) {
        const int par = p & 1;
        // prefetch x(p+1): one dwordx4 gather; floats across BAR to next use
        int tb = tokT[p + 1][r16];
        xn = *(const f4v*)(ebase + tb);
        // L0: h0(p)^T — 2 chains of 2
        f4v A1 = xc;
        A1 = MFMA(wh0h[0], a0[0], A1);
        A1 = MFMA(wh0h[1], a0[1], A1);
        f4v A2 = MFMA(wh0l[0], a0[0], z4);
        A2 = MFMA(wh0l[1], a0[1], A2);
        // L1: h1(p-1)^T — 4 chains of 2 (reuses a0 fragments)
        f4v C1 = b1v;
        C1 = MFMA(wx1h[0], a0[0], C1);
        C1 = MFMA(wx1h[1], a0[1], C1);
        f4v C2 = MFMA(wx1l[0], a0[0], z4);
        C2 = MFMA(wx1l[1], a0[1], C2);
        f4v C3 = MFMA(wh1h[0], a1[0], z4);
        C3 = MFMA(wh1h[1], a1[1], C3);
        f4v C4 = MFMA(wh1l[0], a1[0], z4);
        C4 = MFMA(wh1l[1], a1[1], C4);
        f4v acc0 = A1 + A2;
        f4v acc1 = (C1 + C2) + (C3 + C4);
        f16x4 p0, p1;
#pragma unroll
        for (int q = 0; q < 4; ++q) {
            p0[q] = (_Float16)fast_tanh(acc0[q]);
            p1[q] = (_Float16)fast_tanh(acc1[q]);
        }
        *(f16x4*)&H0[par][r16][jcol] = p0;         // one b64 write each
        *(f16x4*)&H1[par][r16][jcol] = p1;
        xc = xn;
        BAR();
        a0[0] = *(const f16x8*)&H0[par][r16][8 * g];
        a0[1] = *(const f16x8*)&H0[par][r16][32 + 8 * g];
        a1[0] = *(const f16x8*)&H1[par][r16][8 * g];
        a1[1] = *(const f16x8*)&H1[par][r16][32 + 8 * g];
    }

    // ---- p = TT-1 = 79 (par 1): both layers, no prefetch ----
    {
        f4v A1 = xc;
        A1 = MFMA(wh0h[0], a0[0], A1);
        A1 = MFMA(wh0h[1], a0[1], A1);
        f4v A2 = MFMA(wh0l[0], a0[0], z4);
        A2 = MFMA(wh0l[1], a0[1], A2);
        f4v C1 = b1v;
        C1 = MFMA(wx1h[0], a0[0], C1);
        C1 = MFMA(wx1h[1], a0[1], C1);
        f4v C2 = MFMA(wx1l[0], a0[0], z4);
        C2 = MFMA(wx1l[1], a0[1], C2);
        f4v C3 = MFMA(wh1h[0], a1[0], z4);
        C3 = MFMA(wh1h[1], a1[1], C3);
        f4v C4 = MFMA(wh1l[0], a1[0], z4);
        C4 = MFMA(wh1l[1], a1[1], C4);
        f4v acc0 = A1 + A2;
        f4v acc1 = (C1 + C2) + (C3 + C4);
        f16x4 p0, p1;
#pragma unroll
        for (int q = 0; q < 4; ++q) {
            p0[q] = (_Float16)fast_tanh(acc0[q]);
            p1[q] = (_Float16)fast_tanh(acc1[q]);
        }
        *(f16x4*)&H0[1][r16][jcol] = p0;
        *(f16x4*)&H1[1][r16][jcol] = p1;
        BAR();
        a0[0] = *(const f16x8*)&H0[1][r16][8 * g];
        a0[1] = *(const f16x8*)&H0[1][r16][32 + 8 * g];
        a1[0] = *(const f16x8*)&H1[1][r16][8 * g];
        a1[1] = *(const f16x8*)&H1[1][r16][32 + 8 * g];
    }

    // ---- p = TT = 80: L1 only -> h1(79) stays in registers ----
    {
        f4v C1 = b1v;
        C1 = MFMA(wx1h[0], a0[0], C1);
        C1 = MFMA(wx1h[1], a0[1], C1);
        f4v C2 = MFMA(wx1l[0], a0[0], z4);
        C2 = MFMA(wx1l[1], a0[1], C2);
        f4v C3 = MFMA(wh1h[0], a1[0], z4);
        C3 = MFMA(wh1h[1], a1[1], C3);
        f4v C4 = MFMA(wh1l[0], a1[0], z4);
        C4 = MFMA(wh1l[1], a1[1], C4);
        f4v acc1 = (C1 + C2) + (C3 + C4);
        // Epilogue in-register: lane holds h1(79)[r16][jcol..jcol+3]
        float pp = fast_tanh(acc1[0]) * wov[0];
        pp = fmaf(fast_tanh(acc1[1]), wov[1], pp);
        pp = fmaf(fast_tanh(acc1[2]), wov[2], pp);
        pp = fmaf(fast_tanh(acc1[3]), wov[3], pp);
        pp += __shfl_xor(pp, 16, 64);   // sum over g-groups
        pp += __shfl_xor(pp, 32, 64);
        if (l < 16) Pred[wid][l] = pp;
        BAR();
        if (tid < 16) {
            float logit = Pred[0][tid] + Pred[1][tid] + Pred[2][tid] +
                          Pred[3][tid] + bout[0];
            out[R + tid] = __builtin_amdgcn_rcpf(
                1.0f + __builtin_amdgcn_exp2f(-1.4426950408889634f * logit));
        }
    }
}

extern "C" void kernel_launch(void* const* d_in, const int* in_sizes, int n_in,
                              void* d_out, int out_size, void* d_ws, size_t ws_size,
                              hipStream_t stream) {
    const int*   tokens = (const int*)  d_in[0];
    const float* emb    = (const float*)d_in[1];
    const float* Wx0    = (const float*)d_in[2];
    const float* Wh0    = (const float*)d_in[3];
    const float* b0     = (const float*)d_in[4];
    const float* Wx1    = (const float*)d_in[5];
    const float* Wh1    = (const float*)d_in[6];
    const float* b1     = (const float*)d_in[7];
    const float* Wout   = (const float*)d_in[8];
    const float* bout   = (const float*)d_in[9];
    float* out  = (float*)d_out;
    float* emb2 = (float*)d_ws;   // VV*HH floats = 2.56 MB

    emb2_kernel<<<VV / 16, 256, 0, stream>>>(emb, Wx0, b0, emb2);
    rnn_pipe<<<BB / 16, 256, 0, stream>>>(tokens, emb2, Wh0, Wx1, Wh1, b1,
                                          Wout, bout, out);
}